// Round 1
// baseline (78.640 us; speedup 1.0000x reference)
//
#include <hip/hip_runtime.h>

// Problem: N=8192, D=4096
//   inputs  (N, 2D) f32: mean = [:, :D], var = [:, D:]
//   targets (N, D)  f32
//   out = sum((mean - targets)^2 / var) + log(sum(var))   (scalar f32)
// Memory-bound reduction: 384 MB read -> 1 float.

constexpr int N = 8192;
constexpr int D = 4096;
constexpr int BLOCKS = 2048;   // 256 CUs * 8 blocks/CU
constexpr int THREADS = 256;

__global__ __launch_bounds__(THREADS) void loss_partial_kernel(
    const float* __restrict__ inputs,
    const float* __restrict__ targets,
    float* __restrict__ partials)   // [2 * BLOCKS]: s1 then s2
{
    const long long total4 = (long long)N * D / 4;   // 8,388,608 float4 triples
    const long long stride = (long long)gridDim.x * blockDim.x;

    float s1 = 0.0f;  // sum diff^2 / var
    float s2 = 0.0f;  // sum var

    for (long long i = (long long)blockIdx.x * blockDim.x + threadIdx.x;
         i < total4; i += stride) {
        const long long row  = i >> 10;          // D/4 = 1024
        const long long col4 = (i & 1023) << 2;  // column in floats

        const float4 m = *(const float4*)(inputs  + row * (2LL * D) + col4);
        const float4 v = *(const float4*)(inputs  + row * (2LL * D) + D + col4);
        const float4 t = *(const float4*)(targets + (i << 2));

        const float d0 = m.x - t.x;
        const float d1 = m.y - t.y;
        const float d2 = m.z - t.z;
        const float d3 = m.w - t.w;

        s1 += d0 * d0 / v.x;
        s1 += d1 * d1 / v.y;
        s1 += d2 * d2 / v.z;
        s1 += d3 * d3 / v.w;
        s2 += (v.x + v.y) + (v.z + v.w);
    }

    // wave (64-lane) shuffle reduction
    #pragma unroll
    for (int off = 32; off > 0; off >>= 1) {
        s1 += __shfl_down(s1, off, 64);
        s2 += __shfl_down(s2, off, 64);
    }

    __shared__ float l1[THREADS / 64];
    __shared__ float l2[THREADS / 64];
    const int wave = threadIdx.x >> 6;
    const int lane = threadIdx.x & 63;
    if (lane == 0) { l1[wave] = s1; l2[wave] = s2; }
    __syncthreads();

    if (threadIdx.x == 0) {
        float a = l1[0] + l1[1] + l1[2] + l1[3];
        float b = l2[0] + l2[1] + l2[2] + l2[3];
        partials[blockIdx.x]          = a;
        partials[BLOCKS + blockIdx.x] = b;
    }
}

__global__ __launch_bounds__(256) void loss_final_kernel(
    const float* __restrict__ partials,
    float* __restrict__ out)
{
    double s1 = 0.0, s2 = 0.0;
    for (int i = threadIdx.x; i < BLOCKS; i += 256) {
        s1 += (double)partials[i];
        s2 += (double)partials[BLOCKS + i];
    }

    #pragma unroll
    for (int off = 32; off > 0; off >>= 1) {
        s1 += __shfl_down(s1, off, 64);
        s2 += __shfl_down(s2, off, 64);
    }

    __shared__ double l1[4];
    __shared__ double l2[4];
    const int wave = threadIdx.x >> 6;
    const int lane = threadIdx.x & 63;
    if (lane == 0) { l1[wave] = s1; l2[wave] = s2; }
    __syncthreads();

    if (threadIdx.x == 0) {
        const double a = l1[0] + l1[1] + l1[2] + l1[3];
        const double b = l2[0] + l2[1] + l2[2] + l2[3];
        out[0] = (float)(a + log(b));
    }
}

extern "C" void kernel_launch(void* const* d_in, const int* in_sizes, int n_in,
                              void* d_out, int out_size, void* d_ws, size_t ws_size,
                              hipStream_t stream) {
    const float* inputs  = (const float*)d_in[0];
    const float* targets = (const float*)d_in[1];
    float* out      = (float*)d_out;
    float* partials = (float*)d_ws;   // 2 * BLOCKS * 4 = 16 KB

    loss_partial_kernel<<<BLOCKS, THREADS, 0, stream>>>(inputs, targets, partials);
    loss_final_kernel<<<1, 256, 0, stream>>>(partials, out);
}